// Round 8
// baseline (1948.960 us; speedup 1.0000x reference)
//
#include <hip/hip_runtime.h>
#include <hip/hip_bf16.h>

// LogVAE. R7: attack the per-step non-overlap + init cost.
//  - lstm: lgkm-only barrier (no vmcnt drain; hs stores + x prefetch stay in
//    flight). Safe: R4-fail/R5-pass on identical code proved infra flake, not
//    barrier; all barriers uniform. Double-buffer + lgkm drain => race-free.
//  - lstm: 8 x-MFMAs (t+1) + acc re-init issued in the barrier shadow; post-
//    barrier path = ds_read -> 16 Whh MFMAs -> epilogue.
//  - init: wave-uniform scalar reads of x row (was 32 ds_bpermute shfls/row).
//  - 64 WGs x 4 batch, rows {0,4,8,12}, 1 cell/lane epilogue (R6 structure).

#define B_ 256
#define S_ 1024
#define NF_ 32
#define E_ 64
#define H_ 128
#define L_ 64
#define C_ 31

#define ACTS_OFF 0
#define TS_OFF   8118528   // 256*1023*31
#define MU_OFF   8380416   // + 256*1023
#define LV_OFF   8396800   // + 256*64

#define LOG2E  1.44269504f
#define LOG2E2 2.88539008f

typedef __attribute__((ext_vector_type(8))) short short8;
typedef __attribute__((ext_vector_type(4))) float float4v;

__device__ inline unsigned short f2bf(float x){
  union { float f; unsigned u; } a; a.f = x;
  unsigned r = a.u + 0x7FFFu + ((a.u >> 16) & 1u);
  return (unsigned short)(r >> 16);
}
__device__ inline float frcp(float x){
#if __has_builtin(__builtin_amdgcn_rcpf)
  return __builtin_amdgcn_rcpf(x);
#else
  return 1.0f / x;
#endif
}
__device__ inline float fexp2(float x){
#if __has_builtin(__builtin_amdgcn_exp2f)
  return __builtin_amdgcn_exp2f(x);
#else
  return exp2f(x);
#endif
}
__device__ inline float fsig(float x){ return frcp(1.0f + fexp2(-LOG2E*x)); }
__device__ inline float leaky(float x){ return x >= 0.0f ? x : 0.01f*x; }
__device__ inline float wredsum(float v){
  v += __shfl_xor(v, 32, 64);
  v += __shfl_xor(v, 16, 64);
  v += __shfl_xor(v,  8, 64);
  v += __shfl_xor(v,  4, 64);
  v += __shfl_xor(v,  2, 64);
  v += __shfl_xor(v,  1, 64);
  return v;
}
// LDS-only barrier: drain lgkm (h exchange) but leave vmem (hs stores, x
// prefetch) in flight. __syncthreads() forces vmcnt(0) — the R6 ~460cy/step
// stall. "memory" clobber pins compiler ordering of the ds ops around it.
__device__ inline void wg_barrier(){
  asm volatile("s_waitcnt lgkmcnt(0)\n\ts_barrier" ::: "memory");
}

// ---------------- Kernel A: x_emb = LN(leaky(x @ W.T + b)) -> bf16 [S][B][E] --
__global__ __launch_bounds__(256) void init_kernel(
    const float* __restrict__ x, const float* __restrict__ W,
    const float* __restrict__ bias, const float* __restrict__ gam,
    const float* __restrict__ beta, unsigned short* __restrict__ xemb)
{
  // zero the 64-short pad after xemb (stride-0 x-load target for pad lanes)
  if (blockIdx.x == 0 && threadIdx.x < 64)
    xemb[(size_t)S_*B_*E_ + threadIdx.x] = 0;

  const int wave = threadIdx.x >> 6, lane = threadIdx.x & 63;
  const int r = blockIdx.x * 4 + wave;        // r = b*S + s (matches x layout)
  const int b = r >> 10, s = r & 1023;
  const float* xr = x + (size_t)r * NF_;      // wave-uniform row -> scalar loads
  float acc = bias[lane];
  const float* wr = W + lane * NF_;
  #pragma unroll
  for (int k = 0; k < NF_; ++k)
    acc = fmaf(xr[k], wr[k], acc);
  acc = leaky(acc);
  float m = wredsum(acc) * (1.0f/64.0f);
  float d = acc - m;
  float v = wredsum(d*d) * (1.0f/64.0f);
  float y = d * rsqrtf(v + 1e-5f) * gam[lane] + beta[lane];
  xemb[((size_t)s * B_ + b) * E_ + lane] = f2bf(y);   // [S][B][E]
}

// ---------------- Kernel B: LSTM recurrence ---------------------------------
// grid=64 (4 batch/WG), block=512 (8 waves). Wave w owns i,f,g,o gates of
// hidden [16w,16w+16). Batch b_local -> MFMA row 4*b_local; lane (q,c16)
// epilogues exactly reg r=0 (cell = batch q, hidden unit 16w+c16).
__global__ __launch_bounds__(512, 2) void lstm_kernel(
    const float* __restrict__ Wih,   // [512][64]
    const float* __restrict__ Whh,   // [512][128]
    const float* __restrict__ bih, const float* __restrict__ bhh,
    const unsigned short* __restrict__ xemb,  // [S][256][64] bf16 (+64 zero pad)
    int T,
    const float* __restrict__ h0, const float* __restrict__ c0, // null => ones/zeros
    float* __restrict__ hT_out,               // [256][128] fp32 or null
    unsigned short* __restrict__ hs_out)      // [T][256][128] bf16 or null
{
  __shared__ unsigned short hbuf[2][16*136];  // +8 pad/row
  const int tid = threadIdx.x;
  const int wave = tid >> 6, lane = tid & 63;
  const int q = lane >> 4, c16 = lane & 15;
  const int bt0 = blockIdx.x * 4;
  const int hu = wave * 16 + c16;

  // Persistent B frags: kb 0..3 = Whh (K=0..128), kb 4..5 = Wih (K=128..192)
  short8 Bf[4][6];
  float bias[4];
  #pragma unroll
  for (int g = 0; g < 4; ++g){
    const int gcol = g*128 + hu;
    bias[g] = bih[gcol] + bhh[gcol];
    #pragma unroll
    for (int kb = 0; kb < 6; ++kb){
      union { short8 v; unsigned short u[8]; } tmp;
      #pragma unroll
      for (int j = 0; j < 8; ++j){
        int k = kb*32 + q*8 + j;
        float wv = (kb < 4) ? Whh[gcol*H_ + k] : Wih[gcol*E_ + (k - H_)];
        tmp.u[j] = f2bf(wv);
      }
      Bf[g][kb] = tmp.v;
    }
  }

  // LDS: zero both buffers, then fill rows {0,4,8,12} of buf0 with h0.
  unsigned short* hflat = &hbuf[0][0];
  for (int idx = tid; idx < 2*16*136; idx += 512) hflat[idx] = 0;
  __syncthreads();
  {
    int b = tid >> 7, k = tid & 127;   // tid < 512 = 4*128
    hbuf[0][(4*b)*136 + k] = h0 ? f2bf(h0[((size_t)(bt0 + b))*H_ + k])
                                : (unsigned short)0x3F80; // bf16(1.0)
  }
  float cst = c0 ? c0[((size_t)(bt0 + q))*H_ + hu] : 0.0f;
  __syncthreads();

  // x stream: lanes c16%4==0 carry batch c16>>2; others read the zero pad
  // with stride 0 (no per-step re-zeroing, no divergent branch).
  const int is_x = ((c16 & 3) == 0);
  const unsigned short* xp = is_x
      ? (xemb + ((size_t)(bt0 + (c16 >> 2)))*E_ + q*8)
      : (xemb + (size_t)S_*B_*E_ + q*8);
  const size_t xstep = is_x ? (size_t)B_*E_ : 0;

  // Invariants entering iter t: acc = bias + x-proj(t); nxf = x(t+1);
  // xp -> x(min(t+2, T-1)).
  short8 xf0 = *(const short8*)xp;            // x(0)
  short8 xf1 = *(const short8*)(xp + 32);
  xp += xstep;                                // -> x(1)
  short8 nxf0 = *(const short8*)xp;           // x(1)
  short8 nxf1 = *(const short8*)(xp + 32);
  if (T > 2) xp += xstep;                     // -> x(2)

  float4v acc[4];
  #pragma unroll
  for (int g = 0; g < 4; ++g){
    acc[g] = (float4v){bias[g], 0.0f, 0.0f, 0.0f};
    acc[g] = __builtin_amdgcn_mfma_f32_16x16x32_bf16(xf0, Bf[g][4], acc[g], 0, 0, 0);
    acc[g] = __builtin_amdgcn_mfma_f32_16x16x32_bf16(xf1, Bf[g][5], acc[g], 0, 0, 0);
  }

  for (int t = 0; t < T; ++t){
    const int cur = t & 1;
    const unsigned short* hb = hflat + cur*2176;
    short8 Af[4];
    #pragma unroll
    for (int kb = 0; kb < 4; ++kb)
      Af[kb] = *(const short8*)(hb + c16*136 + kb*32 + q*8);
    #pragma unroll
    for (int kb = 0; kb < 4; ++kb){
      #pragma unroll
      for (int g = 0; g < 4; ++g)
        acc[g] = __builtin_amdgcn_mfma_f32_16x16x32_bf16(Af[kb], Bf[g][kb], acc[g], 0, 0, 0);
    }

    // epilogue: 1 cell/lane (reg r=0). Shared-rcp pairs:
    // sig(i)*tanh(g) = e^i(e^2g-1) / [(1+e^i)(1+e^2g)], same for o/c.
    float gi = acc[0][0], gf = acc[1][0], gg = acc[2][0], go = acc[3][0];
    float ei  = fexp2(gi * LOG2E);
    float e2g = fexp2(gg * LOG2E2);
    float t1  = (ei * (e2g - 1.0f)) * frcp((1.0f + ei) * (1.0f + e2g));
    float sf  = fsig(gf);
    float c   = fmaf(sf, cst, t1);
    cst = c;
    float eo  = fexp2(go * LOG2E);
    float e2c = fexp2(fminf(c * LOG2E2, 126.0f));   // clamp: c can accumulate
    float h   = (eo * (e2c - 1.0f)) * frcp((1.0f + eo) * (1.0f + e2c));

    unsigned short* hw = hflat + (1 - cur)*2176;
    unsigned short hb16 = f2bf(h);
    hw[(4*q)*136 + hu] = hb16;
    if (hs_out) hs_out[((size_t)t*B_ + bt0 + q)*H_ + hu] = hb16;
    if (hT_out && t == T-1) hT_out[((size_t)(bt0 + q))*H_ + hu] = h;

    // barrier shadow: rotate x regs, prefetch x(t+2), issue x-MFMAs for t+1.
    xf0 = nxf0; xf1 = nxf1;                   // x(t+1)
    nxf0 = *(const short8*)xp;                // x(min(t+2,T-1))
    nxf1 = *(const short8*)(xp + 32);
    if (t < T - 3) xp += xstep;
    #pragma unroll
    for (int g = 0; g < 4; ++g){
      acc[g] = (float4v){bias[g], 0.0f, 0.0f, 0.0f};
      acc[g] = __builtin_amdgcn_mfma_f32_16x16x32_bf16(xf0, Bf[g][4], acc[g], 0, 0, 0);
      acc[g] = __builtin_amdgcn_mfma_f32_16x16x32_bf16(xf1, Bf[g][5], acc[g], 0, 0, 0);
    }
    wg_barrier();
  }
}

// ---------------- Kernel C: mu/logvar/latent/dh0/dc0 ------------------------
__global__ __launch_bounds__(128) void latent_kernel(
    const float* __restrict__ hT, const float* __restrict__ eps,
    const float* __restrict__ mu_W, const float* __restrict__ mu_b,
    const float* __restrict__ mu_g, const float* __restrict__ mu_be,
    const float* __restrict__ lv_W, const float* __restrict__ lv_b,
    const float* __restrict__ lv_g, const float* __restrict__ lv_be,
    const float* __restrict__ lh_W, const float* __restrict__ lh_b,
    const float* __restrict__ lh_g, const float* __restrict__ lh_be,
    const float* __restrict__ lc_W, const float* __restrict__ lc_b,
    const float* __restrict__ lc_g, const float* __restrict__ lc_be,
    float* __restrict__ out, float* __restrict__ dh0, float* __restrict__ dc0)
{
  const int b = blockIdx.x, tid = threadIdx.x;
  const int wave = tid >> 6, lane = tid & 63;
  __shared__ float shT[H_];
  __shared__ float smu[L_], slv[L_], slat[L_];
  __shared__ float part[2];
  shT[tid] = hT[(size_t)b*H_ + tid];
  __syncthreads();
  {
    const float* W = wave ? lv_W : mu_W;
    float a = (wave ? lv_b : mu_b)[lane];
    for (int k = 0; k < H_; ++k) a += shT[k] * W[lane*H_ + k];
    a = leaky(a);
    float m = wredsum(a) * (1.0f/L_);
    float d = a - m;
    float v = wredsum(d*d) * (1.0f/L_);
    float y = d * rsqrtf(v + 1e-5f) * (wave ? lv_g : mu_g)[lane] + (wave ? lv_be : mu_be)[lane];
    out[(wave ? LV_OFF : MU_OFF) + (size_t)b*L_ + lane] = y;
    if (wave) slv[lane] = y; else smu[lane] = y;
  }
  __syncthreads();
  if (tid < L_) slat[tid] = smu[tid] + eps[(size_t)b*L_ + tid] * expf(0.5f*slv[tid]);
  __syncthreads();
  #pragma unroll 1
  for (int which = 0; which < 2; ++which){
    const float* W = which ? lc_W : lh_W;
    float p = (which ? lc_b : lh_b)[tid];
    for (int k = 0; k < L_; ++k) p += slat[k] * W[tid*L_ + k];
    p = leaky(p);
    float s = wredsum(p);
    if (lane == 0) part[wave] = s;
    __syncthreads();
    float mean = (part[0] + part[1]) * (1.0f/H_);
    __syncthreads();
    float d = p - mean;
    float s2 = wredsum(d*d);
    if (lane == 0) part[wave] = s2;
    __syncthreads();
    float var = (part[0] + part[1]) * (1.0f/H_);
    __syncthreads();
    float y = d * rsqrtf(var + 1e-5f) * (which ? lc_g : lh_g)[tid] + (which ? lc_be : lh_be)[tid];
    (which ? dc0 : dh0)[(size_t)b*H_ + tid] = y;
  }
}

// ---------------- Kernel D: acts/ts heads via MFMA (N=32: 31 acts + ts) -----
__global__ __launch_bounds__(256) void out_kernel(
    const unsigned short* __restrict__ hs,   // [1023][256][128] bf16
    const float* __restrict__ actW, const float* __restrict__ actB,
    const float* __restrict__ timeW, const float* __restrict__ timeB,
    float* __restrict__ out)
{
  const int wave = threadIdx.x >> 6, lane = threadIdx.x & 63;
  const int quad = lane >> 4, c16 = lane & 15;
  const int mt = blockIdx.x * 4 + wave;      // M-tile of 16 rows (r = t*256 + b)
  short8 Wf[2][4]; float biasn[2];
  #pragma unroll
  for (int ti = 0; ti < 2; ++ti){
    const int n = ti*16 + c16;
    biasn[ti] = (n < C_) ? actB[n] : timeB[0];
    #pragma unroll
    for (int kb = 0; kb < 4; ++kb){
      union { short8 v; unsigned short u[8]; } tmp;
      #pragma unroll
      for (int j = 0; j < 8; ++j){
        int k = kb*32 + quad*8 + j;
        tmp.u[j] = f2bf((n < C_) ? actW[n*H_ + k] : timeW[k]);
      }
      Wf[ti][kb] = tmp.v;
    }
  }
  const unsigned short* hp = hs + ((size_t)mt*16 + c16)*H_ + quad*8;
  float4v acc[2];
  #pragma unroll
  for (int ti = 0; ti < 2; ++ti) acc[ti] = (float4v){biasn[ti], biasn[ti], biasn[ti], biasn[ti]};
  #pragma unroll
  for (int kb = 0; kb < 4; ++kb){
    short8 a = *(const short8*)(hp + kb*32);
    acc[0] = __builtin_amdgcn_mfma_f32_16x16x32_bf16(a, Wf[0][kb], acc[0], 0, 0, 0);
    acc[1] = __builtin_amdgcn_mfma_f32_16x16x32_bf16(a, Wf[1][kb], acc[1], 0, 0, 0);
  }
  #pragma unroll
  for (int ti = 0; ti < 2; ++ti){
    const int n = ti*16 + c16;
    #pragma unroll
    for (int r = 0; r < 4; ++r){
      int rr = mt*16 + quad*4 + r;
      int tt = rr >> 8, b = rr & 255;
      float v = acc[ti][r];
      if (n < C_) out[ACTS_OFF + ((size_t)b*1023 + tt)*C_ + n] = v;
      else        out[TS_OFF + (size_t)b*1023 + tt] = v;
    }
  }
}

// ---------------- launch ----------------------------------------------------
extern "C" void kernel_launch(void* const* d_in, const int* in_sizes, int n_in,
                              void* d_out, int out_size, void* d_ws, size_t ws_size,
                              hipStream_t stream)
{
  (void)in_sizes; (void)n_in; (void)out_size; (void)ws_size;
  const float* x       = (const float*)d_in[0];
  const float* eps     = (const float*)d_in[1];
  const float* init_W  = (const float*)d_in[2];
  const float* init_b  = (const float*)d_in[3];
  const float* init_g  = (const float*)d_in[4];
  const float* init_be = (const float*)d_in[5];
  const float* enc_Wih = (const float*)d_in[6];
  const float* enc_Whh = (const float*)d_in[7];
  const float* enc_bih = (const float*)d_in[8];
  const float* enc_bhh = (const float*)d_in[9];
  const float* mu_W  = (const float*)d_in[10];
  const float* mu_b  = (const float*)d_in[11];
  const float* mu_g  = (const float*)d_in[12];
  const float* mu_be = (const float*)d_in[13];
  const float* lv_W  = (const float*)d_in[14];
  const float* lv_b  = (const float*)d_in[15];
  const float* lv_g  = (const float*)d_in[16];
  const float* lv_be = (const float*)d_in[17];
  const float* dec_Wih = (const float*)d_in[18];
  const float* dec_Whh = (const float*)d_in[19];
  const float* dec_bih = (const float*)d_in[20];
  const float* dec_bhh = (const float*)d_in[21];
  const float* lh_W  = (const float*)d_in[22];
  const float* lh_b  = (const float*)d_in[23];
  const float* lh_g  = (const float*)d_in[24];
  const float* lh_be = (const float*)d_in[25];
  const float* lc_W  = (const float*)d_in[26];
  const float* lc_b  = (const float*)d_in[27];
  const float* lc_g  = (const float*)d_in[28];
  const float* lc_be = (const float*)d_in[29];
  const float* act_W  = (const float*)d_in[30];
  const float* act_b  = (const float*)d_in[31];
  const float* time_W = (const float*)d_in[32];
  const float* time_b = (const float*)d_in[33];
  float* out = (float*)d_out;

  // workspace: xemb [1024][256][64] bf16 + 64-short zero pad, hs, hT, dh0, dc0
  unsigned short* xemb = (unsigned short*)d_ws;
  unsigned short* hs   = xemb + (size_t)S_*B_*E_ + 64;       // after pad
  float* hT  = (float*)(hs + (size_t)(S_-1)*B_*H_);
  float* dh0 = hT  + B_*H_;
  float* dc0 = dh0 + B_*H_;

  init_kernel<<<dim3((B_*S_)/4), dim3(256), 0, stream>>>(
      x, init_W, init_b, init_g, init_be, xemb);

  lstm_kernel<<<dim3(64), dim3(512), 0, stream>>>(
      enc_Wih, enc_Whh, enc_bih, enc_bhh, xemb, S_,
      nullptr, nullptr, hT, nullptr);

  latent_kernel<<<dim3(B_), dim3(128), 0, stream>>>(
      hT, eps, mu_W, mu_b, mu_g, mu_be, lv_W, lv_b, lv_g, lv_be,
      lh_W, lh_b, lh_g, lh_be, lc_W, lc_b, lc_g, lc_be, out, dh0, dc0);

  lstm_kernel<<<dim3(64), dim3(512), 0, stream>>>(
      dec_Wih, dec_Whh, dec_bih, dec_bhh, xemb, S_-1,
      dh0, dc0, nullptr, hs);

  out_kernel<<<dim3((B_*(S_-1))/16/4), dim3(256), 0, stream>>>(
      hs, act_W, act_b, time_W, time_b, out);
}

// Round 9
// 1656.917 us; speedup vs baseline: 1.1763x; 1.1763x over previous
//
#include <hip/hip_runtime.h>
#include <hip/hip_bf16.h>

// LogVAE. R8 = consolidation + one isolated change:
//  - lstm: EXACT R6 body (best measured, 595us: x-prefetch early, x-MFMAs
//    after Whh, 64 WGs x 4 batch, 1 cell/lane) with ONLY the loop barrier
//    swapped __syncthreads -> lgkm-only (hs stores + x loads stay in flight;
//    asm barrier proven functionally correct in R7).
//  - init: R7 version (wave-uniform scalar x reads) — proven -80us on "other".
//  - R7's regression diagnosed as the shadow restructure (late x-prefetch
//    shrank the load window + acc chains split across barrier), not the
//    barrier itself; R8 tests that theory.

#define B_ 256
#define S_ 1024
#define NF_ 32
#define E_ 64
#define H_ 128
#define L_ 64
#define C_ 31

#define ACTS_OFF 0
#define TS_OFF   8118528   // 256*1023*31
#define MU_OFF   8380416   // + 256*1023
#define LV_OFF   8396800   // + 256*64

#define LOG2E  1.44269504f
#define LOG2E2 2.88539008f

typedef __attribute__((ext_vector_type(8))) short short8;
typedef __attribute__((ext_vector_type(4))) float float4v;

__device__ inline unsigned short f2bf(float x){
  union { float f; unsigned u; } a; a.f = x;
  unsigned r = a.u + 0x7FFFu + ((a.u >> 16) & 1u);
  return (unsigned short)(r >> 16);
}
__device__ inline float frcp(float x){
#if __has_builtin(__builtin_amdgcn_rcpf)
  return __builtin_amdgcn_rcpf(x);
#else
  return 1.0f / x;
#endif
}
__device__ inline float fexp2(float x){
#if __has_builtin(__builtin_amdgcn_exp2f)
  return __builtin_amdgcn_exp2f(x);
#else
  return exp2f(x);
#endif
}
__device__ inline float fsig(float x){ return frcp(1.0f + fexp2(-LOG2E*x)); }
__device__ inline float leaky(float x){ return x >= 0.0f ? x : 0.01f*x; }
__device__ inline float wredsum(float v){
  v += __shfl_xor(v, 32, 64);
  v += __shfl_xor(v, 16, 64);
  v += __shfl_xor(v,  8, 64);
  v += __shfl_xor(v,  4, 64);
  v += __shfl_xor(v,  2, 64);
  v += __shfl_xor(v,  1, 64);
  return v;
}
// LDS-only barrier: drain lgkm (h exchange) but leave vmem (hs stores, x
// prefetch) in flight; compiler emits vmcnt waits at the actual uses.
__device__ inline void wg_barrier(){
  asm volatile("s_waitcnt lgkmcnt(0)\n\ts_barrier" ::: "memory");
}

// ---------------- Kernel A: x_emb = LN(leaky(x @ W.T + b)) -> bf16 [S][B][E] --
__global__ __launch_bounds__(256) void init_kernel(
    const float* __restrict__ x, const float* __restrict__ W,
    const float* __restrict__ bias, const float* __restrict__ gam,
    const float* __restrict__ beta, unsigned short* __restrict__ xemb)
{
  // zero the 64-short pad after xemb (stride-0 x-load target for pad lanes)
  if (blockIdx.x == 0 && threadIdx.x < 64)
    xemb[(size_t)S_*B_*E_ + threadIdx.x] = 0;

  const int wave = threadIdx.x >> 6, lane = threadIdx.x & 63;
  const int r = blockIdx.x * 4 + wave;        // r = b*S + s (matches x layout)
  const int b = r >> 10, s = r & 1023;
  const float* xr = x + (size_t)r * NF_;      // wave-uniform row -> scalar loads
  float acc = bias[lane];
  const float* wr = W + lane * NF_;
  #pragma unroll
  for (int k = 0; k < NF_; ++k)
    acc = fmaf(xr[k], wr[k], acc);
  acc = leaky(acc);
  float m = wredsum(acc) * (1.0f/64.0f);
  float d = acc - m;
  float v = wredsum(d*d) * (1.0f/64.0f);
  float y = d * rsqrtf(v + 1e-5f) * gam[lane] + beta[lane];
  xemb[((size_t)s * B_ + b) * E_ + lane] = f2bf(y);   // [S][B][E]
}

// ---------------- Kernel B: LSTM recurrence ---------------------------------
// grid=64 (4 batch/WG), block=512 (8 waves). Wave w owns i,f,g,o gates of
// hidden [16w,16w+16). Batch b_local -> MFMA row 4*b_local; lane (q,c16)
// epilogues exactly reg r=0 (cell = batch q, hidden unit 16w+c16).
__global__ __launch_bounds__(512, 2) void lstm_kernel(
    const float* __restrict__ Wih,   // [512][64]
    const float* __restrict__ Whh,   // [512][128]
    const float* __restrict__ bih, const float* __restrict__ bhh,
    const unsigned short* __restrict__ xemb,  // [S][256][64] bf16 (+64 zero pad)
    int T,
    const float* __restrict__ h0, const float* __restrict__ c0, // null => ones/zeros
    float* __restrict__ hT_out,               // [256][128] fp32 or null
    unsigned short* __restrict__ hs_out)      // [T][256][128] bf16 or null
{
  __shared__ unsigned short hbuf[2][16*136];  // +8 pad/row
  const int tid = threadIdx.x;
  const int wave = tid >> 6, lane = tid & 63;
  const int q = lane >> 4, c16 = lane & 15;
  const int bt0 = blockIdx.x * 4;
  const int hu = wave * 16 + c16;

  // Persistent B frags: kb 0..3 = Whh (K=0..128), kb 4..5 = Wih (K=128..192)
  short8 Bf[4][6];
  float bias[4];
  #pragma unroll
  for (int g = 0; g < 4; ++g){
    const int gcol = g*128 + hu;
    bias[g] = bih[gcol] + bhh[gcol];
    #pragma unroll
    for (int kb = 0; kb < 6; ++kb){
      union { short8 v; unsigned short u[8]; } tmp;
      #pragma unroll
      for (int j = 0; j < 8; ++j){
        int k = kb*32 + q*8 + j;
        float wv = (kb < 4) ? Whh[gcol*H_ + k] : Wih[gcol*E_ + (k - H_)];
        tmp.u[j] = f2bf(wv);
      }
      Bf[g][kb] = tmp.v;
    }
  }

  // LDS: zero both buffers, then fill rows {0,4,8,12} of buf0 with h0.
  unsigned short* hflat = &hbuf[0][0];
  for (int idx = tid; idx < 2*16*136; idx += 512) hflat[idx] = 0;
  __syncthreads();
  {
    int b = tid >> 7, k = tid & 127;   // tid < 512 = 4*128
    hbuf[0][(4*b)*136 + k] = h0 ? f2bf(h0[((size_t)(bt0 + b))*H_ + k])
                                : (unsigned short)0x3F80; // bf16(1.0)
  }
  float cst = c0 ? c0[((size_t)(bt0 + q))*H_ + hu] : 0.0f;
  __syncthreads();

  // x prefetch: lanes c16%4==0 carry batch c16>>2; others read the zero pad
  // with stride 0 (no per-step re-zeroing, no divergent branch).
  const int is_x = ((c16 & 3) == 0);
  const unsigned short* xp = is_x
      ? (xemb + ((size_t)(bt0 + (c16 >> 2)))*E_ + q*8)
      : (xemb + (size_t)S_*B_*E_ + q*8);
  const size_t xstep = is_x ? (size_t)B_*E_ : 0;
  short8 xf0 = *(const short8*)xp;
  short8 xf1 = *(const short8*)(xp + 32);
  xp += xstep;   // -> t=1

  for (int t = 0; t < T; ++t){
    const int cur = t & 1;
    const unsigned short* hb = hflat + cur*2176;
    short8 Af[4];
    #pragma unroll
    for (int kb = 0; kb < 4; ++kb)
      Af[kb] = *(const short8*)(hb + c16*136 + kb*32 + q*8);

    // prefetch x for t+1 (clamped) — issued early for a full-iteration window
    short8 nx0 = *(const short8*)xp;
    short8 nx1 = *(const short8*)(xp + 32);
    if (t + 2 < T) xp += xstep;

    float4v acc[4];
    #pragma unroll
    for (int g = 0; g < 4; ++g)
      acc[g] = (float4v){bias[g], 0.0f, 0.0f, 0.0f};
    #pragma unroll
    for (int kb = 0; kb < 4; ++kb){
      #pragma unroll
      for (int g = 0; g < 4; ++g)
        acc[g] = __builtin_amdgcn_mfma_f32_16x16x32_bf16(Af[kb], Bf[g][kb], acc[g], 0, 0, 0);
    }
    #pragma unroll
    for (int g = 0; g < 4; ++g){
      acc[g] = __builtin_amdgcn_mfma_f32_16x16x32_bf16(xf0, Bf[g][4], acc[g], 0, 0, 0);
      acc[g] = __builtin_amdgcn_mfma_f32_16x16x32_bf16(xf1, Bf[g][5], acc[g], 0, 0, 0);
    }

    // epilogue: 1 cell/lane (reg r=0). Shared-rcp pairs:
    // sig(i)*tanh(g) = e^i(e^2g-1) / [(1+e^i)(1+e^2g)], same for o/c.
    float gi = acc[0][0], gf = acc[1][0], gg = acc[2][0], go = acc[3][0];
    float ei  = fexp2(gi * LOG2E);
    float e2g = fexp2(gg * LOG2E2);
    float t1  = (ei * (e2g - 1.0f)) * frcp((1.0f + ei) * (1.0f + e2g));
    float sf  = fsig(gf);
    float c   = fmaf(sf, cst, t1);
    cst = c;
    float eo  = fexp2(go * LOG2E);
    float e2c = fexp2(fminf(c * LOG2E2, 126.0f));   // clamp: c can accumulate
    float h   = (eo * (e2c - 1.0f)) * frcp((1.0f + eo) * (1.0f + e2c));

    unsigned short* hw = hflat + (1 - cur)*2176;
    unsigned short hb16 = f2bf(h);
    hw[(4*q)*136 + hu] = hb16;
    if (hs_out) hs_out[((size_t)t*B_ + bt0 + q)*H_ + hu] = hb16;
    if (hT_out && t == T-1) hT_out[((size_t)(bt0 + q))*H_ + hu] = h;
    xf0 = nx0; xf1 = nx1;
    wg_barrier();   // lgkm-only: the ONE change vs R6's loop
  }
}

// ---------------- Kernel C: mu/logvar/latent/dh0/dc0 ------------------------
__global__ __launch_bounds__(128) void latent_kernel(
    const float* __restrict__ hT, const float* __restrict__ eps,
    const float* __restrict__ mu_W, const float* __restrict__ mu_b,
    const float* __restrict__ mu_g, const float* __restrict__ mu_be,
    const float* __restrict__ lv_W, const float* __restrict__ lv_b,
    const float* __restrict__ lv_g, const float* __restrict__ lv_be,
    const float* __restrict__ lh_W, const float* __restrict__ lh_b,
    const float* __restrict__ lh_g, const float* __restrict__ lh_be,
    const float* __restrict__ lc_W, const float* __restrict__ lc_b,
    const float* __restrict__ lc_g, const float* __restrict__ lc_be,
    float* __restrict__ out, float* __restrict__ dh0, float* __restrict__ dc0)
{
  const int b = blockIdx.x, tid = threadIdx.x;
  const int wave = tid >> 6, lane = tid & 63;
  __shared__ float shT[H_];
  __shared__ float smu[L_], slv[L_], slat[L_];
  __shared__ float part[2];
  shT[tid] = hT[(size_t)b*H_ + tid];
  __syncthreads();
  {
    const float* W = wave ? lv_W : mu_W;
    float a = (wave ? lv_b : mu_b)[lane];
    for (int k = 0; k < H_; ++k) a += shT[k] * W[lane*H_ + k];
    a = leaky(a);
    float m = wredsum(a) * (1.0f/L_);
    float d = a - m;
    float v = wredsum(d*d) * (1.0f/L_);
    float y = d * rsqrtf(v + 1e-5f) * (wave ? lv_g : mu_g)[lane] + (wave ? lv_be : mu_be)[lane];
    out[(wave ? LV_OFF : MU_OFF) + (size_t)b*L_ + lane] = y;
    if (wave) slv[lane] = y; else smu[lane] = y;
  }
  __syncthreads();
  if (tid < L_) slat[tid] = smu[tid] + eps[(size_t)b*L_ + tid] * expf(0.5f*slv[tid]);
  __syncthreads();
  #pragma unroll 1
  for (int which = 0; which < 2; ++which){
    const float* W = which ? lc_W : lh_W;
    float p = (which ? lc_b : lh_b)[tid];
    for (int k = 0; k < L_; ++k) p += slat[k] * W[tid*L_ + k];
    p = leaky(p);
    float s = wredsum(p);
    if (lane == 0) part[wave] = s;
    __syncthreads();
    float mean = (part[0] + part[1]) * (1.0f/H_);
    __syncthreads();
    float d = p - mean;
    float s2 = wredsum(d*d);
    if (lane == 0) part[wave] = s2;
    __syncthreads();
    float var = (part[0] + part[1]) * (1.0f/H_);
    __syncthreads();
    float y = d * rsqrtf(var + 1e-5f) * (which ? lc_g : lh_g)[tid] + (which ? lc_be : lh_be)[tid];
    (which ? dc0 : dh0)[(size_t)b*H_ + tid] = y;
  }
}

// ---------------- Kernel D: acts/ts heads via MFMA (N=32: 31 acts + ts) -----
__global__ __launch_bounds__(256) void out_kernel(
    const unsigned short* __restrict__ hs,   // [1023][256][128] bf16
    const float* __restrict__ actW, const float* __restrict__ actB,
    const float* __restrict__ timeW, const float* __restrict__ timeB,
    float* __restrict__ out)
{
  const int wave = threadIdx.x >> 6, lane = threadIdx.x & 63;
  const int quad = lane >> 4, c16 = lane & 15;
  const int mt = blockIdx.x * 4 + wave;      // M-tile of 16 rows (r = t*256 + b)
  short8 Wf[2][4]; float biasn[2];
  #pragma unroll
  for (int ti = 0; ti < 2; ++ti){
    const int n = ti*16 + c16;
    biasn[ti] = (n < C_) ? actB[n] : timeB[0];
    #pragma unroll
    for (int kb = 0; kb < 4; ++kb){
      union { short8 v; unsigned short u[8]; } tmp;
      #pragma unroll
      for (int j = 0; j < 8; ++j){
        int k = kb*32 + quad*8 + j;
        tmp.u[j] = f2bf((n < C_) ? actW[n*H_ + k] : timeW[k]);
      }
      Wf[ti][kb] = tmp.v;
    }
  }
  const unsigned short* hp = hs + ((size_t)mt*16 + c16)*H_ + quad*8;
  float4v acc[2];
  #pragma unroll
  for (int ti = 0; ti < 2; ++ti) acc[ti] = (float4v){biasn[ti], biasn[ti], biasn[ti], biasn[ti]};
  #pragma unroll
  for (int kb = 0; kb < 4; ++kb){
    short8 a = *(const short8*)(hp + kb*32);
    acc[0] = __builtin_amdgcn_mfma_f32_16x16x32_bf16(a, Wf[0][kb], acc[0], 0, 0, 0);
    acc[1] = __builtin_amdgcn_mfma_f32_16x16x32_bf16(a, Wf[1][kb], acc[1], 0, 0, 0);
  }
  #pragma unroll
  for (int ti = 0; ti < 2; ++ti){
    const int n = ti*16 + c16;
    #pragma unroll
    for (int r = 0; r < 4; ++r){
      int rr = mt*16 + quad*4 + r;
      int tt = rr >> 8, b = rr & 255;
      float v = acc[ti][r];
      if (n < C_) out[ACTS_OFF + ((size_t)b*1023 + tt)*C_ + n] = v;
      else        out[TS_OFF + (size_t)b*1023 + tt] = v;
    }
  }
}

// ---------------- launch ----------------------------------------------------
extern "C" void kernel_launch(void* const* d_in, const int* in_sizes, int n_in,
                              void* d_out, int out_size, void* d_ws, size_t ws_size,
                              hipStream_t stream)
{
  (void)in_sizes; (void)n_in; (void)out_size; (void)ws_size;
  const float* x       = (const float*)d_in[0];
  const float* eps     = (const float*)d_in[1];
  const float* init_W  = (const float*)d_in[2];
  const float* init_b  = (const float*)d_in[3];
  const float* init_g  = (const float*)d_in[4];
  const float* init_be = (const float*)d_in[5];
  const float* enc_Wih = (const float*)d_in[6];
  const float* enc_Whh = (const float*)d_in[7];
  const float* enc_bih = (const float*)d_in[8];
  const float* enc_bhh = (const float*)d_in[9];
  const float* mu_W  = (const float*)d_in[10];
  const float* mu_b  = (const float*)d_in[11];
  const float* mu_g  = (const float*)d_in[12];
  const float* mu_be = (const float*)d_in[13];
  const float* lv_W  = (const float*)d_in[14];
  const float* lv_b  = (const float*)d_in[15];
  const float* lv_g  = (const float*)d_in[16];
  const float* lv_be = (const float*)d_in[17];
  const float* dec_Wih = (const float*)d_in[18];
  const float* dec_Whh = (const float*)d_in[19];
  const float* dec_bih = (const float*)d_in[20];
  const float* dec_bhh = (const float*)d_in[21];
  const float* lh_W  = (const float*)d_in[22];
  const float* lh_b  = (const float*)d_in[23];
  const float* lh_g  = (const float*)d_in[24];
  const float* lh_be = (const float*)d_in[25];
  const float* lc_W  = (const float*)d_in[26];
  const float* lc_b  = (const float*)d_in[27];
  const float* lc_g  = (const float*)d_in[28];
  const float* lc_be = (const float*)d_in[29];
  const float* act_W  = (const float*)d_in[30];
  const float* act_b  = (const float*)d_in[31];
  const float* time_W = (const float*)d_in[32];
  const float* time_b = (const float*)d_in[33];
  float* out = (float*)d_out;

  // workspace: xemb [1024][256][64] bf16 + 64-short zero pad, hs, hT, dh0, dc0
  unsigned short* xemb = (unsigned short*)d_ws;
  unsigned short* hs   = xemb + (size_t)S_*B_*E_ + 64;       // after pad
  float* hT  = (float*)(hs + (size_t)(S_-1)*B_*H_);
  float* dh0 = hT  + B_*H_;
  float* dc0 = dh0 + B_*H_;

  init_kernel<<<dim3((B_*S_)/4), dim3(256), 0, stream>>>(
      x, init_W, init_b, init_g, init_be, xemb);

  lstm_kernel<<<dim3(64), dim3(512), 0, stream>>>(
      enc_Wih, enc_Whh, enc_bih, enc_bhh, xemb, S_,
      nullptr, nullptr, hT, nullptr);

  latent_kernel<<<dim3(B_), dim3(128), 0, stream>>>(
      hT, eps, mu_W, mu_b, mu_g, mu_be, lv_W, lv_b, lv_g, lv_be,
      lh_W, lh_b, lh_g, lh_be, lc_W, lc_b, lc_g, lc_be, out, dh0, dc0);

  lstm_kernel<<<dim3(64), dim3(512), 0, stream>>>(
      dec_Wih, dec_Whh, dec_bih, dec_bhh, xemb, S_-1,
      dh0, dc0, nullptr, hs);

  out_kernel<<<dim3((B_*(S_-1))/16/4), dim3(256), 0, stream>>>(
      hs, act_W, act_b, time_W, time_b, out);
}